// Round 2
// baseline (752.338 us; speedup 1.0000x reference)
//
#include <hip/hip_runtime.h>
#include <hip/hip_bf16.h>

// Problem constants
#define NPIX 12544   // 112*112
#define NKV 196      // 14*14
#define CCH 64

typedef _Float16 half2_t __attribute__((ext_vector_type(2)));

#if defined(__has_builtin)
#if __has_builtin(__builtin_amdgcn_fdot2)
#define HAVE_FDOT2 1
#endif
#endif

__device__ __forceinline__ float dot2acc(half2_t a, half2_t b, float c) {
#ifdef HAVE_FDOT2
  return __builtin_amdgcn_fdot2(a, b, c, false);
#else
  return c + (float)a.x * (float)b.x + (float)a.y * (float)b.y;
#endif
}

union F4H { float4 f; half2_t h[4]; };

// ---------------------------------------------------------------------------
// Transpose [B,C,HW] -> [B,HW,C] for x1 and x2.  grid = 2 tensors * 2 b * 196
__global__ __launch_bounds__(256) void k_transpose_in(
    const float* __restrict__ x1, const float* __restrict__ x2,
    float* __restrict__ x1f, float* __restrict__ x2f) {
  __shared__ float tile[64][65];
  int id = blockIdx.x;
  int tensor = id / 392; int rem = id - tensor * 392;
  int b = rem / 196; int t64 = rem % 196; int n0 = t64 * 64;
  const float* src = tensor ? x2 : x1;
  float* dst = tensor ? x2f : x1f;
  int t = threadIdx.x;
  for (int i = 0; i < 16; ++i) {
    int c = i * 4 + (t >> 6);
    int n = t & 63;
    tile[c][n] = src[(b * 64 + c) * NPIX + n0 + n];
  }
  __syncthreads();
  for (int i = 0; i < 16; ++i) {
    int n = i * 4 + (t >> 6);
    int c = t & 63;
    dst[(b * NPIX + n0 + n) * 64 + c] = tile[c][n];
  }
}

// ---------------------------------------------------------------------------
// srw [co][ci][i][j] -> wt [ij][ci][co]  (per attention).  grid = 4*64 blocks
__global__ __launch_bounds__(256) void k_wtprep(
    const float* __restrict__ s0, const float* __restrict__ s1,
    const float* __restrict__ s2, const float* __restrict__ s3,
    float* __restrict__ wt) {
  __shared__ float tile[64][65];
  int id = blockIdx.x; int a = id >> 6; int ci = id & 63;
  const float* s = (a == 0) ? s0 : (a == 1) ? s1 : (a == 2) ? s2 : s3;
  float* d = wt + a * 262144;
  int t = threadIdx.x;
  for (int i = 0; i < 16; ++i) {
    int co = i * 4 + (t >> 6);
    int ij = t & 63;
    tile[co][ij] = s[co * 4096 + ci * 64 + ij];
  }
  __syncthreads();
  for (int i = 0; i < 16; ++i) {
    int ij = i * 4 + (t >> 6);
    int co = t & 63;
    d[(ij * 64 + ci) * 64 + co] = tile[co][ij];
  }
}

// ---------------------------------------------------------------------------
// Reduction conv as GEMM partials.  grid = 49 pixel-groups * 8 k-slices.
// part[s][p][co], p = flat pixel (b*196 + py*14 + px)
__global__ __launch_bounds__(256) void k_conv(
    const float* __restrict__ xf, const float* __restrict__ wt,
    float* __restrict__ part) {
  __shared__ __align__(16) float act[8 * 8 * 64];  // [pix][ijl][ci]
  __shared__ float red[16][8][65];
  int g = blockIdx.x % 49, s = blockIdx.x / 49;
  int t = threadIdx.x;
  for (int q = 0; q < 4; ++q) {
    int fi = t + 256 * q;            // float4 index 0..1023
    int row = fi >> 4, pos = fi & 15;
    int pix = row >> 3, ijl = row & 7;
    int ij = s * 8 + ijl, ii = ij >> 3, jj = ij & 7;
    int p = g * 8 + pix, b = p / 196, pi = p % 196;
    int py = pi / 14, px = pi % 14;
    const float4* sp = (const float4*)(xf + (size_t)(b * NPIX + (8 * py + ii) * 112 + 8 * px + jj) * 64);
    ((float4*)act)[fi] = sp[pos];
  }
  __syncthreads();
  int coq = t & 15, kp = t >> 4;           // kp 0..15
  int ijl = kp >> 1, ci0 = (kp & 1) * 32;
  float acc[8][4];
#pragma unroll
  for (int p = 0; p < 8; ++p)
#pragma unroll
    for (int c = 0; c < 4; ++c) acc[p][c] = 0.f;
  const float* wb = wt + ((s * 8 + ijl) * 64 + ci0) * 64 + coq * 4;
  const float* ab = act + ijl * 64 + ci0;
  for (int kk = 0; kk < 32; ++kk) {
    float4 w4 = *(const float4*)(wb + kk * 64);
#pragma unroll
    for (int p = 0; p < 8; ++p) {
      float a = ab[p * 512 + kk];
      acc[p][0] += a * w4.x; acc[p][1] += a * w4.y;
      acc[p][2] += a * w4.z; acc[p][3] += a * w4.w;
    }
  }
#pragma unroll
  for (int p = 0; p < 8; ++p)
#pragma unroll
    for (int c = 0; c < 4; ++c) red[kp][p][coq * 4 + c] = acc[p][c];
  __syncthreads();
  for (int q = 0; q < 2; ++q) {
    int oi = t + q * 256;
    int pix = oi >> 6, co = oi & 63;
    float sum = 0.f;
#pragma unroll
    for (int k = 0; k < 16; ++k) sum += red[k][pix][co];
    int p = g * 8 + pix;
    part[(s * 392 + p) * 64 + co] = sum;
  }
}

// ---------------------------------------------------------------------------
// Reduce conv partials, +bias, LayerNorm, KV projection -> f16 K,V.
// grid = 392 (pixel), 128 threads.
__global__ __launch_bounds__(128) void k_lnkv(
    const float* __restrict__ part, const float* __restrict__ srb,
    const float* __restrict__ lng, const float* __restrict__ lnb,
    const float* __restrict__ kvw,
    _Float16* __restrict__ kbuf, _Float16* __restrict__ vbuf) {
  __shared__ __align__(16) float yn[64];
  __shared__ __align__(16) float4 lkvw[16][128];   // [ci4][co2] vectorized
  int p = blockIdx.x, t = threadIdx.x;
  for (int i = 0; i < 64; ++i) {
    int idx = i * 128 + t;
    int co2 = idx >> 6, ci = idx & 63;
    ((float*)lkvw)[(ci >> 2) * 512 + co2 * 4 + (ci & 3)] = kvw[idx];
  }
  if (t < 64) {
    float y = 0.f;
    for (int s = 0; s < 8; ++s) y += part[(s * 392 + p) * 64 + t];
    y += srb[t];
    float s1 = y, s2 = y * y;
#pragma unroll
    for (int off = 32; off; off >>= 1) { s1 += __shfl_xor(s1, off); s2 += __shfl_xor(s2, off); }
    float mean = s1 * 0.015625f;
    float var = s2 * 0.015625f - mean * mean;
    float rs = rsqrtf(var + 1e-5f);
    yn[t] = (y - mean) * rs * lng[t] + lnb[t];
  }
  __syncthreads();
  float acc = 0.f;
#pragma unroll
  for (int c4 = 0; c4 < 16; ++c4) {
    float4 w4 = lkvw[c4][t];
    float4 y4 = *(const float4*)&yn[c4 * 4];
    acc += y4.x * w4.x + y4.y * w4.y + y4.z * w4.z + y4.w * w4.w;
  }
  int b = p / 196, pi = p % 196;
  int h = (t & 63) >> 3, d = t & 7;
  if (t < 64) kbuf[((b * 8 + h) * 196 + pi) * 8 + d] = (_Float16)acc;          // [b][h][m][d]
  else        vbuf[((b * 8 + h) * 8 + d) * 196 + pi] = (_Float16)acc;          // [b][h][d][m]
}

// ---------------------------------------------------------------------------
// Fused attention: q-proj + max-free online softmax + AV + residual + out-proj.
// grid = 784 (32 rows each), 256 threads: t = row*8 + head.
__global__ __launch_bounds__(256) void k_attn(
    const float* __restrict__ xqf,
    const _Float16* __restrict__ kbuf, const _Float16* __restrict__ vbuf,
    const float* __restrict__ qw, const float* __restrict__ pw,
    const float* __restrict__ pb, float* __restrict__ outb) {
  __shared__ __align__(16) float lxq[32][68];
  __shared__ __align__(16) float lqw[64][68];   // row-rotated: co -> (co&7)*8 | co>>3
  __shared__ __align__(16) float lpw[64][68];   // same rotation
  __shared__ __align__(16) float lo[32][68];
  __shared__ float lpb[64];
  int t = threadIdx.x;
  int rb = blockIdx.x * 32;
  for (int i = 0; i < 8; ++i) {
    int idx = i * 256 + t;
    lxq[idx >> 6][idx & 63] = xqf[(size_t)rb * 64 + idx];
  }
  for (int i = 0; i < 16; ++i) {
    int idx = i * 256 + t;
    int co = idx >> 6, ci = idx & 63;
    int lr = ((co & 7) << 3) | (co >> 3);
    lqw[lr][ci] = qw[idx];
    lpw[lr][ci] = pw[idx];
  }
  if (t < 64) lpb[t] = pb[t];
  __syncthreads();
  int r = t >> 3, h = t & 7;
  int gr = rb + r, b = gr / NPIX;
  // q projection (f32): q8[j] = sum_ci xq[ci]*qw[h*8+j][ci]
  float q8[8];
#pragma unroll
  for (int j = 0; j < 8; ++j) q8[j] = 0.f;
#pragma unroll
  for (int c4 = 0; c4 < 16; ++c4) {
    float4 a4 = *(const float4*)&lxq[r][c4 * 4];
#pragma unroll
    for (int j = 0; j < 8; ++j) {
      float4 w4 = *(const float4*)&lqw[j * 8 + h][c4 * 4];
      q8[j] += a4.x * w4.x + a4.y * w4.y + a4.z * w4.z + a4.w * w4.w;
    }
  }
  half2_t qh[4];
#pragma unroll
  for (int j = 0; j < 4; ++j) {
    float s0 = q8[2 * j] * 0.35355339059327373f;      // *hd^-0.5 folded into q
    float s1 = q8[2 * j + 1] * 0.35355339059327373f;
    half2_t v; v.x = (_Float16)s0; v.y = (_Float16)s1;
    qh[j] = v;
  }
  const float4* kp4 = (const float4*)(kbuf + (size_t)(b * 8 + h) * 196 * 8);
  const _Float16* vb = vbuf + (size_t)(b * 8 + h) * 8 * 196;
  float l = 0.f;
  float o8[8];
#pragma unroll
  for (int j = 0; j < 8; ++j) o8[j] = 0.f;
  // max-free online softmax: scores are tiny (|s| < ~0.2), exp cannot overflow
  for (int mp = 0; mp < 98; ++mp) {
    F4H u0, u1;
    u0.f = kp4[2 * mp];
    u1.f = kp4[2 * mp + 1];
    float sc0 = 0.f, sc1 = 0.f;
#pragma unroll
    for (int i = 0; i < 4; ++i) sc0 = dot2acc(qh[i], u0.h[i], sc0);
#pragma unroll
    for (int i = 0; i < 4; ++i) sc1 = dot2acc(qh[i], u1.h[i], sc1);
    float e0 = __expf(sc0), e1 = __expf(sc1);
    l += e0 + e1;
    half2_t ep; ep.x = (_Float16)e0; ep.y = (_Float16)e1;
#pragma unroll
    for (int j = 0; j < 8; ++j) {
      half2_t v2 = *(const half2_t*)(vb + j * 196 + 2 * mp);
      o8[j] = dot2acc(ep, v2, o8[j]);
    }
  }
  float rl = 1.f / l;
#pragma unroll
  for (int j = 0; j < 8; ++j) lo[r][h * 8 + j] = o8[j] * rl;
  __syncthreads();
  // residual add: lo += lxq
  for (int i = 0; i < 8; ++i) {
    int idx = i * 256 + t;
    lo[idx >> 6][idx & 63] += lxq[idx >> 6][idx & 63];
  }
  __syncthreads();
  // out projection: thread (r, cg) computes co = cg*8..cg*8+7
  int cg = t & 7;
  float av[8];
#pragma unroll
  for (int k = 0; k < 8; ++k) av[k] = lpb[cg * 8 + k];
#pragma unroll
  for (int c4 = 0; c4 < 16; ++c4) {
    float4 a4 = *(const float4*)&lo[r][c4 * 4];
#pragma unroll
    for (int k = 0; k < 8; ++k) {
      float4 w4 = *(const float4*)&lpw[k * 8 + cg][c4 * 4];
      av[k] += a4.x * w4.x + a4.y * w4.y + a4.z * w4.z + a4.w * w4.w;
    }
  }
  float* orow = outb + (size_t)gr * 64 + cg * 8;
#pragma unroll
  for (int k = 0; k < 8; ++k) orow[k] = av[k];
}

// ---------------------------------------------------------------------------
// Final projection + transpose back to [B,C,H,W].  grid = 2*196, 256 threads.
__global__ __launch_bounds__(256) void k_final(
    const float* __restrict__ dd, const float* __restrict__ pw,
    const float* __restrict__ pb, float* __restrict__ out) {
  __shared__ __align__(16) float lt[64][68];
  __shared__ __align__(16) float lw[64][68];   // row map: co -> (co&15)*4 | co>>4
  __shared__ float lpb[64];
  int id = blockIdx.x;
  int b = id / 196, t64 = id % 196, n0 = t64 * 64;
  int t = threadIdx.x;
  for (int i = 0; i < 16; ++i) {
    int idx = i * 256 + t;
    int co = idx >> 6, ci = idx & 63;
    int lr = ((co & 15) << 2) | (co >> 4);
    lw[lr][ci] = pw[idx];
  }
  // FIXED: stage the FULL 64x64 input tile (was i < 4 -> only rows 0..15,
  // rows 16..63 were uninitialized LDS => absmax error 0.21)
  for (int i = 0; i < 16; ++i) {
    int idx = i * 256 + t;
    lt[idx >> 6][idx & 63] = dd[(size_t)(b * NPIX + n0) * 64 + idx];
  }
  if (t < 64) lpb[t] = pb[t];
  __syncthreads();
  int n = t >> 2, coq = t & 3;    // thread computes co = coq*16 .. +15 for row n
  float acc[16];
#pragma unroll
  for (int k = 0; k < 16; ++k) acc[k] = lpb[coq * 16 + k];
#pragma unroll
  for (int c4 = 0; c4 < 16; ++c4) {
    float4 a4 = *(const float4*)&lt[n][c4 * 4];
#pragma unroll
    for (int k = 0; k < 16; ++k) {
      float4 w4 = *(const float4*)&lw[k * 4 + coq][c4 * 4];
      acc[k] += a4.x * w4.x + a4.y * w4.y + a4.z * w4.z + a4.w * w4.w;
    }
  }
  __syncthreads();
#pragma unroll
  for (int k = 0; k < 16; ++k) lt[coq * 16 + k][n] = acc[k];
  __syncthreads();
  for (int i = 0; i < 16; ++i) {
    int c = i * 4 + (t >> 6), nn = t & 63;
    out[(size_t)(b * 64 + c) * NPIX + n0 + nn] = lt[c][nn];
  }
}

// ---------------------------------------------------------------------------
extern "C" void kernel_launch(void* const* d_in, const int* in_sizes, int n_in,
                              void* d_out, int out_size, void* d_ws, size_t ws_size,
                              hipStream_t stream) {
  const float* x1 = (const float*)d_in[0];
  const float* x2 = (const float*)d_in[1];
  const float *qw[4], *kvw[4], *pwv[4], *pbv[4], *srw[4], *srb[4], *lng[4], *lnb[4];
  for (int i = 0; i < 4; ++i) {
    const int base = 2 + i * 8;
    qw[i]  = (const float*)d_in[base + 0];
    kvw[i] = (const float*)d_in[base + 1];
    pwv[i] = (const float*)d_in[base + 2];
    pbv[i] = (const float*)d_in[base + 3];
    srw[i] = (const float*)d_in[base + 4];
    srb[i] = (const float*)d_in[base + 5];
    lng[i] = (const float*)d_in[base + 6];
    lnb[i] = (const float*)d_in[base + 7];
  }
  const float* fpw = (const float*)d_in[34];
  const float* fpb = (const float*)d_in[35];
  float* out = (float*)d_out;

  // Workspace layout (buffers aliased across the dependency chain):
  //   slot0: x1f -> b -> d ; slot1: x2f -> c ; slot2: a
  char* ws = (char*)d_ws;
  const size_t SZ = (size_t)2 * NPIX * 64 * 4;       // 6,422,528 B
  float* slot0 = (float*)(ws);
  float* slot1 = (float*)(ws + SZ);
  float* slot2 = (float*)(ws + 2 * SZ);
  float* wt    = (float*)(ws + 3 * SZ);              // 4 * 1 MiB
  float* part  = (float*)(ws + 3 * SZ + 4u * 1048576);   // 802,816 B
  _Float16* kbuf = (_Float16*)(ws + 3 * SZ + 4u * 1048576 + 802816);
  _Float16* vbuf = (_Float16*)(ws + 3 * SZ + 4u * 1048576 + 802816 + 100352);

  float* xf1 = slot0; float* xf2 = slot1;
  float* abuf = slot2; float* bbuf = slot0; float* cbuf = slot1; float* dbuf = slot0;

  k_transpose_in<<<784, 256, 0, stream>>>(x1, x2, xf1, xf2);
  k_wtprep<<<256, 256, 0, stream>>>(srw[0], srw[1], srw[2], srw[3], wt);

  const float* xqs[4] = {xf1, xf2, bbuf, abuf};
  const float* kvs[4] = {xf1, abuf, bbuf, cbuf};
  float* outs[4]      = {abuf, bbuf, cbuf, dbuf};
  for (int i = 0; i < 4; ++i) {
    k_conv<<<392, 256, 0, stream>>>(kvs[i], wt + i * 262144, part);
    k_lnkv<<<392, 128, 0, stream>>>(part, srb[i], lng[i], lnb[i], kvw[i], kbuf, vbuf);
    k_attn<<<784, 256, 0, stream>>>(xqs[i], kbuf, vbuf, qw[i], pwv[i], pbv[i], outs[i]);
  }
  k_final<<<392, 256, 0, stream>>>(dbuf, fpw, fpb, out);
}

// Round 4
// 288.118 us; speedup vs baseline: 2.6112x; 2.6112x over previous
//
#include <hip/hip_runtime.h>
#include <hip/hip_bf16.h>

// Problem constants
#define NPIX 12544   // 112*112
#define NKV 196      // 14*14
#define CCH 64

typedef _Float16 half2_t __attribute__((ext_vector_type(2)));

#if defined(__has_builtin)
#if __has_builtin(__builtin_amdgcn_fdot2)
#define HAVE_FDOT2 1
#endif
#if __has_builtin(__builtin_amdgcn_cvt_pkrtz)
#define HAVE_PKRTZ 1
#endif
#endif

__device__ __forceinline__ float dot2acc(half2_t a, half2_t b, float c) {
#ifdef HAVE_FDOT2
  return __builtin_amdgcn_fdot2(a, b, c, false);
#else
  return c + (float)a.x * (float)b.x + (float)a.y * (float)b.y;
#endif
}

__device__ __forceinline__ half2_t pack2(float a, float b) {
#ifdef HAVE_PKRTZ
  // builtin returns __fp16 ext_vector(2); bit-cast to our _Float16 vector type
  union { __fp16 __attribute__((ext_vector_type(2))) r; half2_t h; } u;
  u.r = __builtin_amdgcn_cvt_pkrtz(a, b);
  return u.h;
#else
  half2_t v; v.x = (_Float16)a; v.y = (_Float16)b; return v;
#endif
}

// q scale: hd^-0.5 * log2(e) so the softmax can use raw exp2 (v_exp_f32)
#define QSCALE 0.5100974012336431f

// ---------------------------------------------------------------------------
// Transpose [B,C,HW] -> [B,HW,C] for x1 and x2.  grid = 2 tensors * 2 b * 196
__global__ __launch_bounds__(256) void k_transpose_in(
    const float* __restrict__ x1, const float* __restrict__ x2,
    float* __restrict__ x1f, float* __restrict__ x2f) {
  __shared__ float tile[64][65];
  int id = blockIdx.x;
  int tensor = id / 392; int rem = id - tensor * 392;
  int b = rem / 196; int t64 = rem % 196; int n0 = t64 * 64;
  const float* src = tensor ? x2 : x1;
  float* dst = tensor ? x2f : x1f;
  int t = threadIdx.x;
  for (int i = 0; i < 16; ++i) {
    int c = i * 4 + (t >> 6);
    int n = t & 63;
    tile[c][n] = src[(b * 64 + c) * NPIX + n0 + n];
  }
  __syncthreads();
  for (int i = 0; i < 16; ++i) {
    int n = i * 4 + (t >> 6);
    int c = t & 63;
    dst[(b * NPIX + n0 + n) * 64 + c] = tile[c][n];
  }
}

// ---------------------------------------------------------------------------
// srw [co][ci][i][j] -> wt [ij][ci][co]  (per attention).  grid = 4*64 blocks
__global__ __launch_bounds__(256) void k_wtprep(
    const float* __restrict__ s0, const float* __restrict__ s1,
    const float* __restrict__ s2, const float* __restrict__ s3,
    float* __restrict__ wt) {
  __shared__ float tile[64][65];
  int id = blockIdx.x; int a = id >> 6; int ci = id & 63;
  const float* s = (a == 0) ? s0 : (a == 1) ? s1 : (a == 2) ? s2 : s3;
  float* d = wt + a * 262144;
  int t = threadIdx.x;
  for (int i = 0; i < 16; ++i) {
    int co = i * 4 + (t >> 6);
    int ij = t & 63;
    tile[co][ij] = s[co * 4096 + ci * 64 + ij];
  }
  __syncthreads();
  for (int i = 0; i < 16; ++i) {
    int ij = i * 4 + (t >> 6);
    int co = t & 63;
    d[(ij * 64 + ci) * 64 + co] = tile[co][ij];
  }
}

// ---------------------------------------------------------------------------
// Reduction conv as GEMM partials.  grid = 49 pixel-groups * 8 k-slices.
// part[s][p][co], p = flat pixel (b*196 + py*14 + px)
__global__ __launch_bounds__(256) void k_conv(
    const float* __restrict__ xf, const float* __restrict__ wt,
    float* __restrict__ part) {
  __shared__ __align__(16) float act[8 * 8 * 64];  // [pix][ijl][ci]
  __shared__ float red[16][8][65];
  int g = blockIdx.x % 49, s = blockIdx.x / 49;
  int t = threadIdx.x;
  for (int q = 0; q < 4; ++q) {
    int fi = t + 256 * q;            // float4 index 0..1023
    int row = fi >> 4, pos = fi & 15;
    int pix = row >> 3, ijl = row & 7;
    int ij = s * 8 + ijl, ii = ij >> 3, jj = ij & 7;
    int p = g * 8 + pix, b = p / 196, pi = p % 196;
    int py = pi / 14, px = pi % 14;
    const float4* sp = (const float4*)(xf + (size_t)(b * NPIX + (8 * py + ii) * 112 + 8 * px + jj) * 64);
    ((float4*)act)[fi] = sp[pos];
  }
  __syncthreads();
  int coq = t & 15, kp = t >> 4;           // kp 0..15
  int ijl = kp >> 1, ci0 = (kp & 1) * 32;
  float acc[8][4];
#pragma unroll
  for (int p = 0; p < 8; ++p)
#pragma unroll
    for (int c = 0; c < 4; ++c) acc[p][c] = 0.f;
  const float* wb = wt + ((s * 8 + ijl) * 64 + ci0) * 64 + coq * 4;
  const float* ab = act + ijl * 64 + ci0;
  for (int kk = 0; kk < 32; ++kk) {
    float4 w4 = *(const float4*)(wb + kk * 64);
#pragma unroll
    for (int p = 0; p < 8; ++p) {
      float a = ab[p * 512 + kk];
      acc[p][0] += a * w4.x; acc[p][1] += a * w4.y;
      acc[p][2] += a * w4.z; acc[p][3] += a * w4.w;
    }
  }
#pragma unroll
  for (int p = 0; p < 8; ++p)
#pragma unroll
    for (int c = 0; c < 4; ++c) red[kp][p][coq * 4 + c] = acc[p][c];
  __syncthreads();
  for (int q = 0; q < 2; ++q) {
    int oi = t + q * 256;
    int pix = oi >> 6, co = oi & 63;
    float sum = 0.f;
#pragma unroll
    for (int k = 0; k < 16; ++k) sum += red[k][pix][co];
    int p = g * 8 + pix;
    part[(s * 392 + p) * 64 + co] = sum;
  }
}

// ---------------------------------------------------------------------------
// Reduce conv partials, +bias, LayerNorm, KV projection -> f16 K,V.
// grid = 392 (pixel), 128 threads.
__global__ __launch_bounds__(128) void k_lnkv(
    const float* __restrict__ part, const float* __restrict__ srb,
    const float* __restrict__ lng, const float* __restrict__ lnb,
    const float* __restrict__ kvw,
    _Float16* __restrict__ kbuf, _Float16* __restrict__ vbuf) {
  __shared__ __align__(16) float yn[64];
  __shared__ __align__(16) float4 lkvw[16][128];   // [ci4][co2] vectorized
  int p = blockIdx.x, t = threadIdx.x;
  for (int i = 0; i < 64; ++i) {
    int idx = i * 128 + t;
    int co2 = idx >> 6, ci = idx & 63;
    ((float*)lkvw)[(ci >> 2) * 512 + co2 * 4 + (ci & 3)] = kvw[idx];
  }
  if (t < 64) {
    float y = 0.f;
    for (int s = 0; s < 8; ++s) y += part[(s * 392 + p) * 64 + t];
    y += srb[t];
    float s1 = y, s2 = y * y;
#pragma unroll
    for (int off = 32; off; off >>= 1) { s1 += __shfl_xor(s1, off); s2 += __shfl_xor(s2, off); }
    float mean = s1 * 0.015625f;
    float var = s2 * 0.015625f - mean * mean;
    float rs = rsqrtf(var + 1e-5f);
    yn[t] = (y - mean) * rs * lng[t] + lnb[t];
  }
  __syncthreads();
  float acc = 0.f;
#pragma unroll
  for (int c4 = 0; c4 < 16; ++c4) {
    float4 w4 = lkvw[c4][t];
    float4 y4 = *(const float4*)&yn[c4 * 4];
    acc += y4.x * w4.x + y4.y * w4.y + y4.z * w4.z + y4.w * w4.w;
  }
  int b = p / 196, pi = p % 196;
  int h = (t & 63) >> 3, d = t & 7;
  if (t < 64) kbuf[((b * 8 + h) * 196 + pi) * 8 + d] = (_Float16)acc;          // [b][h][m][d]
  else        vbuf[((b * 8 + h) * 8 + d) * 196 + pi] = (_Float16)acc;          // [b][h][d][m]
}

// ---------------------------------------------------------------------------
// Q projection -> f16 qbuf [b][h][n][8] with QSCALE folded.
// grid = 784 (32 rows x 8 heads), 256 threads: t = row*8 + head.
__global__ __launch_bounds__(256) void k_qproj(
    const float* __restrict__ xqf, const float* __restrict__ qw,
    _Float16* __restrict__ qbuf) {
  __shared__ __align__(16) float lxq[32][68];
  __shared__ __align__(16) float lqw[64][68];   // row-rotated: co -> (co&7)*8 | co>>3
  int t = threadIdx.x;
  int rb = blockIdx.x * 32;
  for (int i = 0; i < 8; ++i) {
    int idx = i * 256 + t;
    lxq[idx >> 6][idx & 63] = xqf[(size_t)rb * 64 + idx];
  }
  for (int i = 0; i < 16; ++i) {
    int idx = i * 256 + t;
    int co = idx >> 6, ci = idx & 63;
    int lr = ((co & 7) << 3) | (co >> 3);
    lqw[lr][ci] = qw[idx];
  }
  __syncthreads();
  int r = t >> 3, h = t & 7;
  int gr = rb + r, b = gr / NPIX, n = gr - b * NPIX;
  float q8[8];
#pragma unroll
  for (int j = 0; j < 8; ++j) q8[j] = 0.f;
#pragma unroll
  for (int c4 = 0; c4 < 16; ++c4) {
    float4 a4 = *(const float4*)&lxq[r][c4 * 4];
#pragma unroll
    for (int j = 0; j < 8; ++j) {
      float4 w4 = *(const float4*)&lqw[j * 8 + h][c4 * 4];
      q8[j] += a4.x * w4.x + a4.y * w4.y + a4.z * w4.z + a4.w * w4.w;
    }
  }
  union { uint4 u; half2_t h2[4]; } qp;
#pragma unroll
  for (int j = 0; j < 4; ++j)
    qp.h2[j] = pack2(q8[2 * j] * QSCALE, q8[2 * j + 1] * QSCALE);
  *(uint4*)(qbuf + ((size_t)(b * 8 + h) * NPIX + n) * 8) = qp.u;
}

// ---------------------------------------------------------------------------
// Attention core: per (b,h), K/V staged in LDS (6.3 KB), one row per lane.
// All K/V reads are uniform-address broadcasts.  grid = 16*(12544/256) = 784.
__global__ __launch_bounds__(256) void k_score_av(
    const _Float16* __restrict__ qbuf, const _Float16* __restrict__ kbuf,
    const _Float16* __restrict__ vbuf, float* __restrict__ obuf) {
  __shared__ __align__(16) uint4 lK[196];     // K rows: [m][8 halfs] = 16B each
  __shared__ uint lV[8 * 98];                 // V: [d][196 halfs] as u32 pairs
  int blk = blockIdx.x;
  int bh = blk / 49, tile = blk - bh * 49;
  int t = threadIdx.x;
  const uint4* kg = (const uint4*)(kbuf + (size_t)bh * 1568);
  if (t < 196) lK[t] = kg[t];
  const uint* vg = (const uint*)(vbuf + (size_t)bh * 1568);
  for (int i = t; i < 784; i += 256) lV[i] = vg[i];
  __syncthreads();
  int n = tile * 256 + t;
  union { uint4 u; half2_t h2[4]; } q;
  q.u = *(const uint4*)(qbuf + ((size_t)bh * NPIX + n) * 8);
  float l = 0.f;
  float o8[8];
#pragma unroll
  for (int j = 0; j < 8; ++j) o8[j] = 0.f;
  // max-free online softmax (scores tiny); q pre-scaled by hd^-0.5*log2e -> exp2
#pragma unroll 2
  for (int mp = 0; mp < 98; ++mp) {
    union { uint4 u; half2_t h2[4]; } k0, k1;
    k0.u = lK[2 * mp];
    k1.u = lK[2 * mp + 1];
    float s0 = 0.f, s1 = 0.f;
#pragma unroll
    for (int i = 0; i < 4; ++i) s0 = dot2acc(q.h2[i], k0.h2[i], s0);
#pragma unroll
    for (int i = 0; i < 4; ++i) s1 = dot2acc(q.h2[i], k1.h2[i], s1);
    float e0 = exp2f(s0), e1 = exp2f(s1);
    l += e0 + e1;
    half2_t ep = pack2(e0, e1);
#pragma unroll
    for (int j = 0; j < 8; ++j) {
      uint vv = lV[j * 98 + mp];
      o8[j] = dot2acc(ep, *(half2_t*)&vv, o8[j]);
    }
  }
  float rl = 1.f / l;
  int b = bh >> 3, h = bh & 7;
  float* op = obuf + ((size_t)b * NPIX + n) * 64 + h * 8;
  float4 w0, w1;
  w0.x = o8[0] * rl; w0.y = o8[1] * rl; w0.z = o8[2] * rl; w0.w = o8[3] * rl;
  w1.x = o8[4] * rl; w1.y = o8[5] * rl; w1.z = o8[6] * rl; w1.w = o8[7] * rl;
  *(float4*)op = w0;
  *(float4*)(op + 4) = w1;
}

// ---------------------------------------------------------------------------
// Out projection + residual: out = (o + xq) @ pw^T + pb.  grid = 392, 256 thr.
__global__ __launch_bounds__(256) void k_outproj(
    const float* __restrict__ obuf, const float* __restrict__ xqf,
    const float* __restrict__ pw, const float* __restrict__ pb,
    float* __restrict__ outb) {
  __shared__ __align__(16) float lt[64][68];
  __shared__ __align__(16) float lw[64][68];   // row map: co -> (co&15)*4 | co>>4
  __shared__ float lpb[64];
  int t = threadIdx.x;
  size_t base = (size_t)blockIdx.x * 64 * 64;
  for (int i = 0; i < 16; ++i) {
    int idx = i * 256 + t;
    int co = idx >> 6, ci = idx & 63;
    int lr = ((co & 15) << 2) | (co >> 4);
    lw[lr][ci] = pw[idx];
  }
  for (int i = 0; i < 16; ++i) {
    int idx = i * 256 + t;
    lt[idx >> 6][idx & 63] = obuf[base + idx] + xqf[base + idx];
  }
  if (t < 64) lpb[t] = pb[t];
  __syncthreads();
  int n = t >> 2, coq = t & 3;    // thread computes co = coq*16 .. +15 for row n
  float acc[16];
#pragma unroll
  for (int k = 0; k < 16; ++k) acc[k] = lpb[coq * 16 + k];
#pragma unroll
  for (int c4 = 0; c4 < 16; ++c4) {
    float4 a4 = *(const float4*)&lt[n][c4 * 4];
#pragma unroll
    for (int k = 0; k < 16; ++k) {
      float4 w4 = *(const float4*)&lw[k * 4 + coq][c4 * 4];
      acc[k] += a4.x * w4.x + a4.y * w4.y + a4.z * w4.z + a4.w * w4.w;
    }
  }
  float* orow = outb + base + (size_t)n * 64 + coq * 16;
#pragma unroll
  for (int k = 0; k < 4; ++k)
    *(float4*)(orow + k * 4) = *(float4*)&acc[k * 4];
}

// ---------------------------------------------------------------------------
// Final projection + transpose back to [B,C,H,W].  grid = 2*196, 256 threads.
__global__ __launch_bounds__(256) void k_final(
    const float* __restrict__ dd, const float* __restrict__ pw,
    const float* __restrict__ pb, float* __restrict__ out) {
  __shared__ __align__(16) float lt[64][68];
  __shared__ __align__(16) float lw[64][68];   // row map: co -> (co&15)*4 | co>>4
  __shared__ float lpb[64];
  int id = blockIdx.x;
  int b = id / 196, t64 = id % 196, n0 = t64 * 64;
  int t = threadIdx.x;
  for (int i = 0; i < 16; ++i) {
    int idx = i * 256 + t;
    int co = idx >> 6, ci = idx & 63;
    int lr = ((co & 15) << 2) | (co >> 4);
    lw[lr][ci] = pw[idx];
  }
  for (int i = 0; i < 16; ++i) {
    int idx = i * 256 + t;
    lt[idx >> 6][idx & 63] = dd[(size_t)(b * NPIX + n0) * 64 + idx];
  }
  if (t < 64) lpb[t] = pb[t];
  __syncthreads();
  int n = t >> 2, coq = t & 3;    // thread computes co = coq*16 .. +15 for row n
  float acc[16];
#pragma unroll
  for (int k = 0; k < 16; ++k) acc[k] = lpb[coq * 16 + k];
#pragma unroll
  for (int c4 = 0; c4 < 16; ++c4) {
    float4 a4 = *(const float4*)&lt[n][c4 * 4];
#pragma unroll
    for (int k = 0; k < 16; ++k) {
      float4 w4 = *(const float4*)&lw[k * 4 + coq][c4 * 4];
      acc[k] += a4.x * w4.x + a4.y * w4.y + a4.z * w4.z + a4.w * w4.w;
    }
  }
  __syncthreads();
#pragma unroll
  for (int k = 0; k < 16; ++k) lt[coq * 16 + k][n] = acc[k];
  __syncthreads();
  for (int i = 0; i < 16; ++i) {
    int c = i * 4 + (t >> 6), nn = t & 63;
    out[(size_t)(b * 64 + c) * NPIX + n0 + nn] = lt[c][nn];
  }
}

// ---------------------------------------------------------------------------
extern "C" void kernel_launch(void* const* d_in, const int* in_sizes, int n_in,
                              void* d_out, int out_size, void* d_ws, size_t ws_size,
                              hipStream_t stream) {
  const float* x1 = (const float*)d_in[0];
  const float* x2 = (const float*)d_in[1];
  const float *qw[4], *kvw[4], *pwv[4], *pbv[4], *srw[4], *srb[4], *lng[4], *lnb[4];
  for (int i = 0; i < 4; ++i) {
    const int base = 2 + i * 8;
    qw[i]  = (const float*)d_in[base + 0];
    kvw[i] = (const float*)d_in[base + 1];
    pwv[i] = (const float*)d_in[base + 2];
    pbv[i] = (const float*)d_in[base + 3];
    srw[i] = (const float*)d_in[base + 4];
    srb[i] = (const float*)d_in[base + 5];
    lng[i] = (const float*)d_in[base + 6];
    lnb[i] = (const float*)d_in[base + 7];
  }
  const float* fpw = (const float*)d_in[34];
  const float* fpb = (const float*)d_in[35];
  float* out = (float*)d_out;

  // Workspace layout:
  //   slot0: x1f -> b -> d ; slot1: x2f -> c ; slot2: a
  //   wt (4 MiB), part (0.8 MB), kbuf/vbuf (50 KB each, f16),
  //   qbuf (3.2 MB f16), obuf (6.4 MB f32) — all reused per attention.
  char* ws = (char*)d_ws;
  const size_t SZ = (size_t)2 * NPIX * 64 * 4;       // 6,422,528 B
  float* slot0 = (float*)(ws);
  float* slot1 = (float*)(ws + SZ);
  float* slot2 = (float*)(ws + 2 * SZ);
  size_t off = 3 * SZ;
  float* wt    = (float*)(ws + off); off += 4u * 1048576;
  float* part  = (float*)(ws + off); off += 802816;
  _Float16* kbuf = (_Float16*)(ws + off); off += 50176;
  _Float16* vbuf = (_Float16*)(ws + off); off += 50176;
  _Float16* qbuf = (_Float16*)(ws + off); off += (size_t)2 * 8 * NPIX * 8 * 2;
  float* obuf    = (float*)(ws + off); off += (size_t)2 * NPIX * 64 * 4;

  float* xf1 = slot0; float* xf2 = slot1;
  float* abuf = slot2; float* bbuf = slot0; float* cbuf = slot1; float* dbuf = slot0;

  k_transpose_in<<<784, 256, 0, stream>>>(x1, x2, xf1, xf2);
  k_wtprep<<<256, 256, 0, stream>>>(srw[0], srw[1], srw[2], srw[3], wt);

  const float* xqs[4] = {xf1, xf2, bbuf, abuf};
  const float* kvs[4] = {xf1, abuf, bbuf, cbuf};
  float* outs[4]      = {abuf, bbuf, cbuf, dbuf};
  for (int i = 0; i < 4; ++i) {
    k_conv<<<392, 256, 0, stream>>>(kvs[i], wt + i * 262144, part);
    k_lnkv<<<392, 128, 0, stream>>>(part, srb[i], lng[i], lnb[i], kvw[i], kbuf, vbuf);
    k_qproj<<<784, 256, 0, stream>>>(xqs[i], qw[i], qbuf);
    k_score_av<<<784, 256, 0, stream>>>(qbuf, kbuf, vbuf, obuf);
    k_outproj<<<392, 256, 0, stream>>>(obuf, xqs[i], pwv[i], pbv[i], outs[i]);
  }
  k_final<<<392, 256, 0, stream>>>(dbuf, fpw, fpb, out);
}

// Round 5
// 257.704 us; speedup vs baseline: 2.9194x; 1.1180x over previous
//
#include <hip/hip_runtime.h>
#include <hip/hip_bf16.h>

// Problem constants
#define NPIX 12544   // 112*112
#define NKV 196      // 14*14
#define CCH 64

typedef _Float16 half2_t __attribute__((ext_vector_type(2)));
typedef __fp16 fp16v2_t __attribute__((ext_vector_type(2)));

#if defined(__has_builtin)
#if __has_builtin(__builtin_amdgcn_fdot2)
#define HAVE_FDOT2 1
#endif
#if __has_builtin(__builtin_amdgcn_cvt_pkrtz)
#define HAVE_PKRTZ 1
#endif
#if __has_builtin(__builtin_amdgcn_exp2f)
#define HAVE_EXP2 1
#endif
#endif

__device__ __forceinline__ float dot2acc(half2_t a, half2_t b, float c) {
#ifdef HAVE_FDOT2
  return __builtin_amdgcn_fdot2(a, b, c, false);
#else
  return c + (float)a.x * (float)b.x + (float)a.y * (float)b.y;
#endif
}

__device__ __forceinline__ half2_t pack2(float a, float b) {
#ifdef HAVE_PKRTZ
  union { fp16v2_t r; half2_t h; } u;
  u.r = __builtin_amdgcn_cvt_pkrtz(a, b);
  return u.h;
#else
  half2_t v; v.x = (_Float16)a; v.y = (_Float16)b; return v;
#endif
}

__device__ __forceinline__ half2_t as_h2(uint u) {
  union { uint v; half2_t h; } c; c.v = u; return c.h;
}
__device__ __forceinline__ uint h2u(half2_t h) {
  union { half2_t h; uint v; } c; c.h = h; return c.v;
}
__device__ __forceinline__ float fexp2(float x) {
#ifdef HAVE_EXP2
  return __builtin_amdgcn_exp2f(x);
#else
  return exp2f(x);
#endif
}

// q scale: hd^-0.5 * log2(e) so the softmax can use raw exp2 (v_exp_f32)
#define QSCALE 0.5100974012336431f

// ---------------------------------------------------------------------------
// Transpose [B,C,HW] -> [B,HW,C] for x1 and x2.  grid = 2 tensors * 2 b * 196
__global__ __launch_bounds__(256) void k_transpose_in(
    const float* __restrict__ x1, const float* __restrict__ x2,
    float* __restrict__ x1f, float* __restrict__ x2f) {
  __shared__ float tile[64][65];
  int id = blockIdx.x;
  int tensor = id / 392; int rem = id - tensor * 392;
  int b = rem / 196; int t64 = rem % 196; int n0 = t64 * 64;
  const float* src = tensor ? x2 : x1;
  float* dst = tensor ? x2f : x1f;
  int t = threadIdx.x;
  for (int i = 0; i < 16; ++i) {
    int c = i * 4 + (t >> 6);
    int n = t & 63;
    tile[c][n] = src[(b * 64 + c) * NPIX + n0 + n];
  }
  __syncthreads();
  for (int i = 0; i < 16; ++i) {
    int n = i * 4 + (t >> 6);
    int c = t & 63;
    dst[(b * NPIX + n0 + n) * 64 + c] = tile[c][n];
  }
}

// ---------------------------------------------------------------------------
// srw [co][ci][i][j] -> wt [ij][ci][co]  (per attention).  grid = 4*64 blocks
__global__ __launch_bounds__(256) void k_wtprep(
    const float* __restrict__ s0, const float* __restrict__ s1,
    const float* __restrict__ s2, const float* __restrict__ s3,
    float* __restrict__ wt) {
  __shared__ float tile[64][65];
  int id = blockIdx.x; int a = id >> 6; int ci = id & 63;
  const float* s = (a == 0) ? s0 : (a == 1) ? s1 : (a == 2) ? s2 : s3;
  float* d = wt + a * 262144;
  int t = threadIdx.x;
  for (int i = 0; i < 16; ++i) {
    int co = i * 4 + (t >> 6);
    int ij = t & 63;
    tile[co][ij] = s[co * 4096 + ci * 64 + ij];
  }
  __syncthreads();
  for (int i = 0; i < 16; ++i) {
    int ij = i * 4 + (t >> 6);
    int co = t & 63;
    d[(ij * 64 + ci) * 64 + co] = tile[co][ij];
  }
}

// ---------------------------------------------------------------------------
// Combined final weights: pwc = fpw @ pw4 (row-major), pbc = fpb + fpw @ pb4.
// One block, 256 threads.
__global__ __launch_bounds__(256) void k_wcomb(
    const float* __restrict__ fpw, const float* __restrict__ fpb,
    const float* __restrict__ pw4, const float* __restrict__ pb4,
    float* __restrict__ pwc, float* __restrict__ pbc) {
  __shared__ float A[64][65];   // fpw
  __shared__ float B[64][65];   // pw4
  __shared__ float bb[64];
  int t = threadIdx.x;
  for (int i = 0; i < 16; ++i) {
    int idx = i * 256 + t;
    A[idx >> 6][idx & 63] = fpw[idx];
    B[idx >> 6][idx & 63] = pw4[idx];
  }
  if (t < 64) bb[t] = pb4[t];
  __syncthreads();
  int i = t >> 2, jq = t & 3;
  float acc[16];
#pragma unroll
  for (int jj = 0; jj < 16; ++jj) acc[jj] = 0.f;
  for (int k = 0; k < 64; ++k) {
    float a = A[i][k];
#pragma unroll
    for (int jj = 0; jj < 16; ++jj) acc[jj] += a * B[k][jq * 16 + jj];
  }
#pragma unroll
  for (int jj = 0; jj < 16; ++jj) pwc[i * 64 + jq * 16 + jj] = acc[jj];
  if (t < 64) {
    float s = fpb[t];
    for (int k = 0; k < 64; ++k) s += A[t][k] * bb[k];
    pbc[t] = s;
  }
}

// ---------------------------------------------------------------------------
// Reduction conv as GEMM partials.  grid = 49 pixel-groups * 8 k-slices.
// part[s][p][co], p = flat pixel (b*196 + py*14 + px)
__global__ __launch_bounds__(256) void k_conv(
    const float* __restrict__ xf, const float* __restrict__ wt,
    float* __restrict__ part) {
  __shared__ __align__(16) float act[8 * 8 * 64];  // [pix][ijl][ci]
  __shared__ float red[16][8][65];
  int g = blockIdx.x % 49, s = blockIdx.x / 49;
  int t = threadIdx.x;
  for (int q = 0; q < 4; ++q) {
    int fi = t + 256 * q;            // float4 index 0..1023
    int row = fi >> 4, pos = fi & 15;
    int pix = row >> 3, ijl = row & 7;
    int ij = s * 8 + ijl, ii = ij >> 3, jj = ij & 7;
    int p = g * 8 + pix, b = p / 196, pi = p % 196;
    int py = pi / 14, px = pi % 14;
    const float4* sp = (const float4*)(xf + (size_t)(b * NPIX + (8 * py + ii) * 112 + 8 * px + jj) * 64);
    ((float4*)act)[fi] = sp[pos];
  }
  __syncthreads();
  int coq = t & 15, kp = t >> 4;           // kp 0..15
  int ijl = kp >> 1, ci0 = (kp & 1) * 32;
  float acc[8][4];
#pragma unroll
  for (int p = 0; p < 8; ++p)
#pragma unroll
    for (int c = 0; c < 4; ++c) acc[p][c] = 0.f;
  const float* wb = wt + ((s * 8 + ijl) * 64 + ci0) * 64 + coq * 4;
  const float* ab = act + ijl * 64 + ci0;
  for (int kk = 0; kk < 32; ++kk) {
    float4 w4 = *(const float4*)(wb + kk * 64);
#pragma unroll
    for (int p = 0; p < 8; ++p) {
      float a = ab[p * 512 + kk];
      acc[p][0] += a * w4.x; acc[p][1] += a * w4.y;
      acc[p][2] += a * w4.z; acc[p][3] += a * w4.w;
    }
  }
#pragma unroll
  for (int p = 0; p < 8; ++p)
#pragma unroll
    for (int c = 0; c < 4; ++c) red[kp][p][coq * 4 + c] = acc[p][c];
  __syncthreads();
  for (int q = 0; q < 2; ++q) {
    int oi = t + q * 256;
    int pix = oi >> 6, co = oi & 63;
    float sum = 0.f;
#pragma unroll
    for (int k = 0; k < 16; ++k) sum += red[k][pix][co];
    int p = g * 8 + pix;
    part[(s * 392 + p) * 64 + co] = sum;
  }
}

// ---------------------------------------------------------------------------
// Reduce conv partials, +bias, LayerNorm, KV projection -> f16 K,V.
// grid = 392 (pixel), 128 threads.
__global__ __launch_bounds__(128) void k_lnkv(
    const float* __restrict__ part, const float* __restrict__ srb,
    const float* __restrict__ lng, const float* __restrict__ lnb,
    const float* __restrict__ kvw,
    _Float16* __restrict__ kbuf, _Float16* __restrict__ vbuf) {
  __shared__ __align__(16) float yn[64];
  __shared__ __align__(16) float4 lkvw[16][128];   // [ci4][co2] vectorized
  int p = blockIdx.x, t = threadIdx.x;
  for (int i = 0; i < 64; ++i) {
    int idx = i * 128 + t;
    int co2 = idx >> 6, ci = idx & 63;
    ((float*)lkvw)[(ci >> 2) * 512 + co2 * 4 + (ci & 3)] = kvw[idx];
  }
  if (t < 64) {
    float y = 0.f;
    for (int s = 0; s < 8; ++s) y += part[(s * 392 + p) * 64 + t];
    y += srb[t];
    float s1 = y, s2 = y * y;
#pragma unroll
    for (int off = 32; off; off >>= 1) { s1 += __shfl_xor(s1, off); s2 += __shfl_xor(s2, off); }
    float mean = s1 * 0.015625f;
    float var = s2 * 0.015625f - mean * mean;
    float rs = rsqrtf(var + 1e-5f);
    yn[t] = (y - mean) * rs * lng[t] + lnb[t];
  }
  __syncthreads();
  float acc = 0.f;
#pragma unroll
  for (int c4 = 0; c4 < 16; ++c4) {
    float4 w4 = lkvw[c4][t];
    float4 y4 = *(const float4*)&yn[c4 * 4];
    acc += y4.x * w4.x + y4.y * w4.y + y4.z * w4.z + y4.w * w4.w;
  }
  int b = p / 196, pi = p % 196;
  int h = (t & 63) >> 3, d = t & 7;
  if (t < 64) kbuf[((b * 8 + h) * 196 + pi) * 8 + d] = (_Float16)acc;          // [b][h][m][d]
  else        vbuf[((b * 8 + h) * 8 + d) * 196 + pi] = (_Float16)acc;          // [b][h][d][m]
}

// ---------------------------------------------------------------------------
// Fused q-proj + attention core.  grid = 16 bh * 49 tiles = 784, 256 threads.
// Thread t handles row n = tile*256 + t for head h = bh&7.
// LDS: xq tile f16 (33-pad, conflict-free), q-weights (QSCALE folded,
// transposed [c2][8] -> 2 uniform b128 per step), K/V per (b,h) broadcast.
__global__ __launch_bounds__(256) void k_score(
    const float* __restrict__ xqf, const float* __restrict__ qw,
    const _Float16* __restrict__ kbuf, const _Float16* __restrict__ vbuf,
    float* __restrict__ obuf) {
  __shared__ uint lx[256][33];                // [row][c2] f16 pairs
  __shared__ __align__(16) uint lqw[32][8];   // [c2][j] f16 pairs, scaled
  __shared__ __align__(16) uint4 lK[196];     // K rows, 8 halfs = 16B
  __shared__ __align__(8) uint lV[8 * 98];    // V [d][m-pairs]
  int blk = blockIdx.x;
  int bh = blk / 49, tile = blk - bh * 49;
  int b = bh >> 3, h = bh & 7;
  int t = threadIdx.x;
  const float2* xg = (const float2*)(xqf + ((size_t)b * NPIX + tile * 256) * 64);
  for (int i = 0; i < 32; ++i) {
    int idx = i * 256 + t;                    // float2 index over 256x32
    float2 v = xg[idx];
    lx[idx >> 5][idx & 31] = h2u(pack2(v.x, v.y));
  }
  {
    int j = t & 7, c2 = t >> 3;               // 256 = 32 c2 * 8 j
    float2 wv = *(const float2*)(qw + (h * 8 + j) * 64 + c2 * 2);
    lqw[c2][j] = h2u(pack2(wv.x * QSCALE, wv.y * QSCALE));
  }
  const uint4* kg = (const uint4*)(kbuf + (size_t)bh * 1568);
  if (t < 196) lK[t] = kg[t];
  const uint* vg = (const uint*)(vbuf + (size_t)bh * 1568);
  for (int i = t; i < 784; i += 256) lV[i] = vg[i];
  __syncthreads();
  // q projection for own row (f16 dot2, QSCALE already in weights)
  float q8[8];
#pragma unroll
  for (int j = 0; j < 8; ++j) q8[j] = 0.f;
#pragma unroll
  for (int c2 = 0; c2 < 32; ++c2) {
    half2_t xv = as_h2(lx[t][c2]);
    uint4 w0 = *(const uint4*)&lqw[c2][0];
    uint4 w1 = *(const uint4*)&lqw[c2][4];
    q8[0] = dot2acc(xv, as_h2(w0.x), q8[0]);
    q8[1] = dot2acc(xv, as_h2(w0.y), q8[1]);
    q8[2] = dot2acc(xv, as_h2(w0.z), q8[2]);
    q8[3] = dot2acc(xv, as_h2(w0.w), q8[3]);
    q8[4] = dot2acc(xv, as_h2(w1.x), q8[4]);
    q8[5] = dot2acc(xv, as_h2(w1.y), q8[5]);
    q8[6] = dot2acc(xv, as_h2(w1.z), q8[6]);
    q8[7] = dot2acc(xv, as_h2(w1.w), q8[7]);
  }
  half2_t qh[4];
#pragma unroll
  for (int i = 0; i < 4; ++i) qh[i] = pack2(q8[2 * i], q8[2 * i + 1]);
  // max-free online softmax (scores tiny, exp2-domain), 4 m per iter
  float l = 0.f;
  float o8[8];
#pragma unroll
  for (int j = 0; j < 8; ++j) o8[j] = 0.f;
  for (int m4 = 0; m4 < 49; ++m4) {
    union { uint4 u; half2_t h2[4]; } k0, k1, k2, k3;
    k0.u = lK[4 * m4 + 0]; k1.u = lK[4 * m4 + 1];
    k2.u = lK[4 * m4 + 2]; k3.u = lK[4 * m4 + 3];
    float s0 = 0.f, s1 = 0.f, s2 = 0.f, s3 = 0.f;
#pragma unroll
    for (int i = 0; i < 4; ++i) {
      s0 = dot2acc(qh[i], k0.h2[i], s0);
      s1 = dot2acc(qh[i], k1.h2[i], s1);
      s2 = dot2acc(qh[i], k2.h2[i], s2);
      s3 = dot2acc(qh[i], k3.h2[i], s3);
    }
    float e0 = fexp2(s0), e1 = fexp2(s1), e2 = fexp2(s2), e3 = fexp2(s3);
    l += (e0 + e1) + (e2 + e3);
    half2_t ep01 = pack2(e0, e1), ep23 = pack2(e2, e3);
#pragma unroll
    for (int d = 0; d < 8; ++d) {
      uint2 vv = *(const uint2*)&lV[d * 98 + 2 * m4];
      o8[d] = dot2acc(ep01, as_h2(vv.x), o8[d]);
      o8[d] = dot2acc(ep23, as_h2(vv.y), o8[d]);
    }
  }
  float rl = 1.f / l;
  int n = tile * 256 + t;
  float* op = obuf + ((size_t)b * NPIX + n) * 64 + h * 8;
  float4 w0, w1;
  w0.x = o8[0] * rl; w0.y = o8[1] * rl; w0.z = o8[2] * rl; w0.w = o8[3] * rl;
  w1.x = o8[4] * rl; w1.y = o8[5] * rl; w1.z = o8[6] * rl; w1.w = o8[7] * rl;
  *(float4*)op = w0;
  *(float4*)(op + 4) = w1;
}

// ---------------------------------------------------------------------------
// Out projection + residual: out = (o + xq) @ pw^T + pb.  grid = 392, 256 thr.
__global__ __launch_bounds__(256) void k_outproj(
    const float* __restrict__ obuf, const float* __restrict__ xqf,
    const float* __restrict__ pw, const float* __restrict__ pb,
    float* __restrict__ outb) {
  __shared__ __align__(16) float lt[64][68];
  __shared__ __align__(16) float lw[64][68];   // row map: co -> (co&15)*4 | co>>4
  __shared__ float lpb[64];
  int t = threadIdx.x;
  size_t base = (size_t)blockIdx.x * 64 * 64;
  for (int i = 0; i < 16; ++i) {
    int idx = i * 256 + t;
    int co = idx >> 6, ci = idx & 63;
    int lr = ((co & 15) << 2) | (co >> 4);
    lw[lr][ci] = pw[idx];
  }
  for (int i = 0; i < 16; ++i) {
    int idx = i * 256 + t;
    lt[idx >> 6][idx & 63] = obuf[base + idx] + xqf[base + idx];
  }
  if (t < 64) lpb[t] = pb[t];
  __syncthreads();
  int n = t >> 2, coq = t & 3;    // thread computes co = coq*16 .. +15 for row n
  float acc[16];
#pragma unroll
  for (int k = 0; k < 16; ++k) acc[k] = lpb[coq * 16 + k];
#pragma unroll
  for (int c4 = 0; c4 < 16; ++c4) {
    float4 a4 = *(const float4*)&lt[n][c4 * 4];
#pragma unroll
    for (int k = 0; k < 16; ++k) {
      float4 w4 = *(const float4*)&lw[k * 4 + coq][c4 * 4];
      acc[k] += a4.x * w4.x + a4.y * w4.y + a4.z * w4.z + a4.w * w4.w;
    }
  }
  float* orow = outb + base + (size_t)n * 64 + coq * 16;
#pragma unroll
  for (int k = 0; k < 4; ++k)
    *(float4*)(orow + k * 4) = *(float4*)&acc[k * 4];
}

// ---------------------------------------------------------------------------
// Attention-4 out-proj fused with final projection (combined weights) and
// NCHW transpose-store.  grid = 2*196, 256 threads.
__global__ __launch_bounds__(256) void k_outproj_final(
    const float* __restrict__ obuf, const float* __restrict__ xqf,
    const float* __restrict__ pwc, const float* __restrict__ pbc,
    float* __restrict__ out) {
  __shared__ __align__(16) float lt[64][68];
  __shared__ __align__(16) float lw[64][68];   // row map: co -> (co&15)*4 | co>>4
  __shared__ float lpb[64];
  int id = blockIdx.x;
  int b = id / 196, t64 = id % 196, n0 = t64 * 64;
  int t = threadIdx.x;
  size_t base = ((size_t)b * NPIX + n0) * 64;
  for (int i = 0; i < 16; ++i) {
    int idx = i * 256 + t;
    int co = idx >> 6, ci = idx & 63;
    int lr = ((co & 15) << 2) | (co >> 4);
    lw[lr][ci] = pwc[idx];
  }
  for (int i = 0; i < 16; ++i) {
    int idx = i * 256 + t;
    lt[idx >> 6][idx & 63] = obuf[base + idx] + xqf[base + idx];
  }
  if (t < 64) lpb[t] = pbc[t];
  __syncthreads();
  int n = t >> 2, coq = t & 3;
  float acc[16];
#pragma unroll
  for (int k = 0; k < 16; ++k) acc[k] = lpb[coq * 16 + k];
#pragma unroll
  for (int c4 = 0; c4 < 16; ++c4) {
    float4 a4 = *(const float4*)&lt[n][c4 * 4];
#pragma unroll
    for (int k = 0; k < 16; ++k) {
      float4 w4 = *(const float4*)&lw[k * 4 + coq][c4 * 4];
      acc[k] += a4.x * w4.x + a4.y * w4.y + a4.z * w4.z + a4.w * w4.w;
    }
  }
  __syncthreads();
#pragma unroll
  for (int k = 0; k < 16; ++k) lt[coq * 16 + k][n] = acc[k];
  __syncthreads();
  for (int i = 0; i < 16; ++i) {
    int c = i * 4 + (t >> 6), nn = t & 63;
    out[(size_t)(b * 64 + c) * NPIX + n0 + nn] = lt[c][nn];
  }
}

// ---------------------------------------------------------------------------
extern "C" void kernel_launch(void* const* d_in, const int* in_sizes, int n_in,
                              void* d_out, int out_size, void* d_ws, size_t ws_size,
                              hipStream_t stream) {
  const float* x1 = (const float*)d_in[0];
  const float* x2 = (const float*)d_in[1];
  const float *qw[4], *kvw[4], *pwv[4], *pbv[4], *srw[4], *srb[4], *lng[4], *lnb[4];
  for (int i = 0; i < 4; ++i) {
    const int base = 2 + i * 8;
    qw[i]  = (const float*)d_in[base + 0];
    kvw[i] = (const float*)d_in[base + 1];
    pwv[i] = (const float*)d_in[base + 2];
    pbv[i] = (const float*)d_in[base + 3];
    srw[i] = (const float*)d_in[base + 4];
    srb[i] = (const float*)d_in[base + 5];
    lng[i] = (const float*)d_in[base + 6];
    lnb[i] = (const float*)d_in[base + 7];
  }
  const float* fpw = (const float*)d_in[34];
  const float* fpb = (const float*)d_in[35];
  float* out = (float*)d_out;

  // Workspace layout:
  //   slot0: x1f -> b ; slot1: x2f -> c ; slot2: a
  //   wt (4 MiB), part, kbuf/vbuf (f16), obuf, pwc/pbc (combined final)
  char* ws = (char*)d_ws;
  const size_t SZ = (size_t)2 * NPIX * 64 * 4;       // 6,422,528 B
  float* slot0 = (float*)(ws);
  float* slot1 = (float*)(ws + SZ);
  float* slot2 = (float*)(ws + 2 * SZ);
  size_t off = 3 * SZ;
  float* wt    = (float*)(ws + off); off += 4u * 1048576;
  float* part  = (float*)(ws + off); off += 802816;
  _Float16* kbuf = (_Float16*)(ws + off); off += 50176;
  _Float16* vbuf = (_Float16*)(ws + off); off += 50176;
  float* obuf  = (float*)(ws + off); off += SZ;
  float* pwc   = (float*)(ws + off); off += 16384;
  float* pbc   = (float*)(ws + off); off += 256;

  float* xf1 = slot0; float* xf2 = slot1;
  float* abuf = slot2; float* bbuf = slot0; float* cbuf = slot1;

  k_transpose_in<<<784, 256, 0, stream>>>(x1, x2, xf1, xf2);
  k_wtprep<<<256, 256, 0, stream>>>(srw[0], srw[1], srw[2], srw[3], wt);
  k_wcomb<<<1, 256, 0, stream>>>(fpw, fpb, pwv[3], pbv[3], pwc, pbc);

  const float* xqs[4] = {xf1, xf2, bbuf, abuf};
  const float* kvs[4] = {xf1, abuf, bbuf, cbuf};
  float* outs[3]      = {abuf, bbuf, cbuf};
  for (int i = 0; i < 4; ++i) {
    k_conv<<<392, 256, 0, stream>>>(kvs[i], wt + i * 262144, part);
    k_lnkv<<<392, 128, 0, stream>>>(part, srb[i], lng[i], lnb[i], kvw[i], kbuf, vbuf);
    k_score<<<784, 256, 0, stream>>>(xqs[i], qw[i], kbuf, vbuf, obuf);
    if (i < 3)
      k_outproj<<<392, 256, 0, stream>>>(obuf, xqs[i], pwv[i], pbv[i], outs[i]);
    else
      k_outproj_final<<<392, 256, 0, stream>>>(obuf, xqs[3], pwc, pbc, out);
  }
}